// Round 6
// baseline (462.787 us; speedup 1.0000x reference)
//
#include <hip/hip_runtime.h>
#include <hip/hip_bf16.h>
#include <cstdint>
#include <cstddef>

#define SCALE 0.42044820762685725f  // 32^(-1/4)

typedef __attribute__((ext_vector_type(8))) short short8;
typedef __attribute__((ext_vector_type(4))) short short4v;
typedef __attribute__((ext_vector_type(4))) float f32x4;

__device__ __forceinline__ unsigned int pk2bf(float lo, float hi) {
    __hip_bfloat162 h = __float22bfloat162_rn(float2{lo, hi});  // v_cvt_pk_bf16_f32
    unsigned int u;
    __builtin_memcpy(&u, &h, sizeof(u));
    return u;
}
__device__ __forceinline__ unsigned short f2bf(float f) {
    unsigned int u = __builtin_bit_cast(unsigned int, f);
    u = (u + 0x7fffu + ((u >> 16) & 1u)) >> 16;   // RNE
    return (unsigned short)u;
}
__device__ __forceinline__ float bf2f(unsigned short h) {
    unsigned int u = ((unsigned int)h) << 16;
    return __builtin_bit_cast(float, u);
}

// ---------------- prepack ----------------
// [0, 393216) bytes: W A-frags bf16. mtg 0..31: KV rows 256+mtg*16; mtg 32..47: Q rows (mtg-32)*16.
//   idx = ((mtg*8+ks)*64+lane)*8+j <-> W[row(mtg)+(lane&15)][ks*32+(lane>>4)*8+j]
// [393216, 425984): posT bf16 [k=64][m=256]: posT[k*256+m] = bf16(pos[m*64+k])
__global__ __launch_bounds__(256) void prepack_w(const float* __restrict__ w,
                                                 const float* __restrict__ pos,
                                                 unsigned short* __restrict__ wp,
                                                 unsigned short* __restrict__ pT) {
    int gid = blockIdx.x * 256 + threadIdx.x;    // < 40960
    if (gid < 24576) {
        int lane = gid & 63;
        int ks   = (gid >> 6) & 7;
        int mtg  = gid >> 9;                     // 0..47
        int row  = (mtg < 32 ? 256 + mtg * 16 : (mtg - 32) * 16) + (lane & 15);
        int k0   = ks * 32 + (lane >> 4) * 8;
        const float* src = w + row * 256 + k0;
        short8 v;
#pragma unroll
        for (int j = 0; j < 8; ++j) v[j] = (short)f2bf(src[j]);
        *reinterpret_cast<short8*>(wp + (size_t)gid * 8) = v;
    } else {
        int u = gid - 24576;                     // k*256 + m, < 16384
        pT[u] = f2bf(pos[(u & 255) * 64 + (u >> 8)]);
    }
}

// ---------------- main fused kernel: one WG per 2 wq-consecutive tiles ----------------
// Both x tiles staged up-front (one barrier per WG); everything after is wave-local.
// Wave w owns kv rows [64w,64w+64) and heads {2w,2w+1}; attention fully in-register.
template <bool PRE>
__global__ __launch_bounds__(256, 2) void attn_fused(
        const float* __restrict__ x, const float* __restrict__ proj_w,
        const float* __restrict__ proj_b, const float* __restrict__ pos,
        const unsigned short* __restrict__ wpack, const unsigned short* __restrict__ posT,
        float* __restrict__ out) {
    __shared__ __align__(16) unsigned char s_x[2][32768];  // bf16 [p=64][c=256], XOR swizzled
    __shared__ float s_qbias[256];
    __shared__ float s_vbias[256];

    const int t    = threadIdx.x;
    const int lane = t & 63;
    const int wave = t >> 6;
    const int l15  = lane & 15;
    const int l4   = lane >> 4;

    s_qbias[t] = proj_b[t];          // wave-local index ranges: no barrier needed
    s_vbias[t] = proj_b[512 + t];

    // XCD-chunked swizzle: each XCD gets 128 consecutive WGs = 256 consecutive tiles
    const int bid   = blockIdx.x;                       // < 1024
    const int tile0 = ((bid & 7) * 128 + (bid >> 3)) * 2;

    // ---- pos prefetch (tile-invariant): 16 x 8B, held in 16 VGPRs for the whole WG ----
    short4v pos4[4][4];
    if (PRE) {
#pragma unroll
        for (int nt = 0; nt < 4; ++nt)
#pragma unroll
            for (int mt = 0; mt < 4; ++mt)
                pos4[nt][mt] = *reinterpret_cast<const short4v*>(
                    posT + (size_t)(nt * 16 + l15) * 256 + wave * 64 + mt * 16 + l4 * 4);
    }

    // ---- stage BOTH x tiles -> bf16 [p][c] swizzled LDS; single barrier ----
    {
        const int p   = lane;
        const int pl  = lane & 1;
        const int px0 = lane & ~1;
#pragma unroll
        for (int ti = 0; ti < 2; ++ti) {
            const int tile = tile0 + ti;
            const int b = tile >> 8, hq = (tile >> 4) & 15, wq = tile & 15;
            const float* xpx = x + (size_t)b * 4194304 + (size_t)(hq * 8) * 128 + wq * 8
                                 + (px0 >> 3) * 128 + (px0 & 7);
            unsigned char* base = s_x[ti];
#pragma unroll
            for (int h = 0; h < 8; ++h) {
                float2 v[4];
#pragma unroll
                for (int j = 0; j < 4; ++j) {
                    int c = h * 32 + wave * 8 + 2 * j + pl;
                    v[j] = *reinterpret_cast<const float2*>(xpx + (size_t)c * 16384);
                }
                uint4 pk;
                unsigned int* pku = &pk.x;
#pragma unroll
                for (int j = 0; j < 4; ++j) {
                    float sel   = pl ? v[j].x : v[j].y;
                    float other = __shfl_xor(sel, 1);
                    pku[j] = pl ? pk2bf(other, v[j].y) : pk2bf(v[j].x, other);
                }
                int c8 = h * 4 + wave;
                *reinterpret_cast<uint4*>(base + p * 512 + ((c8 * 16) ^ ((p & 7) << 4))) = pk;
            }
        }
    }
    __syncthreads();   // the only barrier

    // A-frag loader (PRE: packed 16B; else: convert on the fly)
    auto ldfrag = [&](int mtg, int ks) -> short8 {
        if (PRE) {
            return *reinterpret_cast<const short8*>(
                wpack + ((size_t)((mtg * 8 + ks) * 64 + lane)) * 8);
        } else {
            int row = (mtg < 32 ? 256 + mtg * 16 : (mtg - 32) * 16) + l15;
            const float* src = proj_w + row * 256 + ks * 32 + l4 * 8;
            short8 v;
#pragma unroll
            for (int j = 0; j < 8; ++j) v[j] = (short)f2bf(src[j]);
            return v;
        }
    };

#pragma unroll 1
    for (int ti = 0; ti < 2; ++ti) {
        const int tile = tile0 + ti;
        const int b = tile >> 8, hq = (tile >> 4) & 15, wq = tile & 15;
        const unsigned char* xl = s_x[ti];

        f32x4 acc[4][4], accQ[4];
        unsigned int kpk[4][4][2];

        // ---- pass 1: keys (rows 256..511) + q (rows 0..255, B-cols 0..15) ----
        // depth-1 software pipeline on W frags (all indices compile-time)
#pragma unroll
        for (int mt = 0; mt < 4; ++mt) {
            accQ[mt] = (f32x4){0.f, 0.f, 0.f, 0.f};
#pragma unroll
            for (int nt = 0; nt < 4; ++nt) acc[mt][nt] = (f32x4){0.f, 0.f, 0.f, 0.f};
        }
        {
            short8 fK[2][4], fQ[2][4];
#pragma unroll
            for (int mt = 0; mt < 4; ++mt) {
                fK[0][mt] = ldfrag(wave * 4 + mt, 0);
                fQ[0][mt] = ldfrag(32 + wave * 4 + mt, 0);
            }
#pragma unroll
            for (int ks = 0; ks < 8; ++ks) {
                const int cur = ks & 1, nxt = cur ^ 1;
                short8 bfr[4];
#pragma unroll
                for (int nt = 0; nt < 4; ++nt) {
                    int n  = nt * 16 + l15;
                    int kb = ks * 32 + l4 * 8;
                    bfr[nt] = *reinterpret_cast<const short8*>(
                        xl + n * 512 + ((2 * kb) ^ ((n & 7) << 4)));
                }
                if (ks < 7) {
#pragma unroll
                    for (int mt = 0; mt < 4; ++mt) {
                        fK[nxt][mt] = ldfrag(wave * 4 + mt, ks + 1);
                        fQ[nxt][mt] = ldfrag(32 + wave * 4 + mt, ks + 1);
                    }
                }
#pragma unroll
                for (int mt = 0; mt < 4; ++mt)
#pragma unroll
                    for (int nt = 0; nt < 4; ++nt)
                        acc[mt][nt] = __builtin_amdgcn_mfma_f32_16x16x32_bf16(
                            fK[cur][mt], bfr[nt], acc[mt][nt], 0, 0, 0);
#pragma unroll
                for (int mt = 0; mt < 4; ++mt)
                    accQ[mt] = __builtin_amdgcn_mfma_f32_16x16x32_bf16(
                        fQ[cur][mt], bfr[0], accQ[mt], 0, 0, 0);
            }
        }

        // pack keys to bf16 regs (no key bias: softmax shift-invariant)
#pragma unroll
        for (int mt = 0; mt < 4; ++mt)
#pragma unroll
            for (int nt = 0; nt < 4; ++nt) {
                kpk[mt][nt][0] = pk2bf(acc[mt][nt][0], acc[mt][nt][1]);
                kpk[mt][nt][1] = pk2bf(acc[mt][nt][2], acc[mt][nt][3]);
            }

        // ---- pass 2: values (rows 512..767), reuse acc; same pipeline ----
#pragma unroll
        for (int mt = 0; mt < 4; ++mt)
#pragma unroll
            for (int nt = 0; nt < 4; ++nt) acc[mt][nt] = (f32x4){0.f, 0.f, 0.f, 0.f};
        {
            short8 fV[2][4];
#pragma unroll
            for (int mt = 0; mt < 4; ++mt) fV[0][mt] = ldfrag(16 + wave * 4 + mt, 0);
#pragma unroll
            for (int ks = 0; ks < 8; ++ks) {
                const int cur = ks & 1, nxt = cur ^ 1;
                short8 bfr[4];
#pragma unroll
                for (int nt = 0; nt < 4; ++nt) {
                    int n  = nt * 16 + l15;
                    int kb = ks * 32 + l4 * 8;
                    bfr[nt] = *reinterpret_cast<const short8*>(
                        xl + n * 512 + ((2 * kb) ^ ((n & 7) << 4)));
                }
                if (ks < 7) {
#pragma unroll
                    for (int mt = 0; mt < 4; ++mt) fV[nxt][mt] = ldfrag(16 + wave * 4 + mt, ks + 1);
                }
#pragma unroll
                for (int mt = 0; mt < 4; ++mt)
#pragma unroll
                    for (int nt = 0; nt < 4; ++nt)
                        acc[mt][nt] = __builtin_amdgcn_mfma_f32_16x16x32_bf16(
                            fV[cur][mt], bfr[nt], acc[mt][nt], 0, 0, 0);
            }
        }

        // ---- attention: fully in-register ----
        float qv[4][4];
#pragma unroll
        for (int mt = 0; mt < 4; ++mt)
#pragma unroll
            for (int i = 0; i < 4; ++i)
                qv[mt][i] = SCALE * (__shfl(accQ[mt][i], lane & 48)
                                     + s_qbias[wave * 64 + mt * 16 + l4 * 4 + i]);

        float lg[2][4], attnw[2][4];
#pragma unroll
        for (int hs = 0; hs < 2; ++hs)
#pragma unroll
            for (int nt = 0; nt < 4; ++nt) {
                float p = 0.f;
#pragma unroll
                for (int mh = 0; mh < 2; ++mh) {
                    int mt = hs * 2 + mh;
                    float kf[4];
                    kf[0] = bf2f((unsigned short)(kpk[mt][nt][0] & 0xffffu));
                    kf[1] = bf2f((unsigned short)(kpk[mt][nt][0] >> 16));
                    kf[2] = bf2f((unsigned short)(kpk[mt][nt][1] & 0xffffu));
                    kf[3] = bf2f((unsigned short)(kpk[mt][nt][1] >> 16));
#pragma unroll
                    for (int i = 0; i < 4; ++i) {
                        float pf = PRE ? bf2f((unsigned short)pos4[nt][mt][i])
                                       : pos[(size_t)(wave * 64 + mt * 16 + l4 * 4 + i) * 64 + nt * 16 + l15];
                        p = fmaf(qv[mt][i], fmaf(SCALE, kf[i], pf), p);
                    }
                }
                p += __shfl_xor(p, 16);   // reduce over d-groups (l4)
                p += __shfl_xor(p, 32);
                lg[hs][nt] = p;
            }
#pragma unroll
        for (int hs = 0; hs < 2; ++hs) {
            float mx = fmaxf(fmaxf(lg[hs][0], lg[hs][1]), fmaxf(lg[hs][2], lg[hs][3]));
            mx = fmaxf(mx, __shfl_xor(mx, 1));
            mx = fmaxf(mx, __shfl_xor(mx, 2));
            mx = fmaxf(mx, __shfl_xor(mx, 4));
            mx = fmaxf(mx, __shfl_xor(mx, 8));
            float e0 = __expf(lg[hs][0] - mx), e1 = __expf(lg[hs][1] - mx);
            float e2 = __expf(lg[hs][2] - mx), e3 = __expf(lg[hs][3] - mx);
            float s = (e0 + e1) + (e2 + e3);
            s += __shfl_xor(s, 1);
            s += __shfl_xor(s, 2);
            s += __shfl_xor(s, 4);
            s += __shfl_xor(s, 8);
            float rs = 1.f / s;
            attnw[hs][0] = e0 * rs; attnw[hs][1] = e1 * rs;
            attnw[hs][2] = e2 * rs; attnw[hs][3] = e3 * rs;
        }

        // ---- epilogue: out = attn @ values from own acc; Σattn=1 folds value bias ----
#pragma unroll
        for (int mt = 0; mt < 4; ++mt) {
            int hs = mt >> 1;
#pragma unroll
            for (int i = 0; i < 4; ++i) {
                float sum = attnw[hs][0] * acc[mt][0][i] + attnw[hs][1] * acc[mt][1][i]
                          + attnw[hs][2] * acc[mt][2][i] + attnw[hs][3] * acc[mt][3][i];
                sum += __shfl_xor(sum, 1);
                sum += __shfl_xor(sum, 2);
                sum += __shfl_xor(sum, 4);
                sum += __shfl_xor(sum, 8);
                if (l15 == 0) {
                    int vr = wave * 64 + mt * 16 + l4 * 4 + i;
                    out[(size_t)b * 65536 + (size_t)vr * 256 + hq * 16 + wq] = sum + s_vbias[vr];
                }
            }
        }
    }
}

extern "C" void kernel_launch(void* const* d_in, const int* in_sizes, int n_in,
                              void* d_out, int out_size, void* d_ws, size_t ws_size,
                              hipStream_t stream) {
    (void)in_sizes; (void)n_in; (void)out_size;
    const float* x      = (const float*)d_in[0];
    const float* proj_w = (const float*)d_in[1];
    const float* proj_b = (const float*)d_in[2];
    const float* pos    = (const float*)d_in[3];
    float* out = (float*)d_out;

    const size_t need_ws = 393216 + 32768;   // A-frags bf16 + posT bf16
    if (d_ws != nullptr && ws_size >= need_ws) {
        unsigned short* wp = (unsigned short*)d_ws;
        unsigned short* pT = (unsigned short*)((char*)d_ws + 393216);
        prepack_w<<<160, 256, 0, stream>>>(proj_w, pos, wp, pT);
        attn_fused<true><<<1024, 256, 0, stream>>>(x, proj_w, proj_b, pos, wp, pT, out);
    } else {
        attn_fused<false><<<1024, 256, 0, stream>>>(x, proj_w, proj_b, pos, nullptr, nullptr, out);
    }
}

// Round 7
// 130.084 us; speedup vs baseline: 3.5576x; 3.5576x over previous
//
#include <hip/hip_runtime.h>
#include <hip/hip_bf16.h>
#include <cstdint>
#include <cstddef>

#define SCALE 0.42044820762685725f  // 32^(-1/4)

typedef __attribute__((ext_vector_type(8))) short short8;
typedef __attribute__((ext_vector_type(4))) short short4v;
typedef __attribute__((ext_vector_type(4))) float f32x4;

__device__ __forceinline__ unsigned int pk2bf(float lo, float hi) {
    __hip_bfloat162 h = __float22bfloat162_rn(float2{lo, hi});  // v_cvt_pk_bf16_f32
    unsigned int u;
    __builtin_memcpy(&u, &h, sizeof(u));
    return u;
}
__device__ __forceinline__ unsigned short f2bf(float f) {
    unsigned int u = __builtin_bit_cast(unsigned int, f);
    u = (u + 0x7fffu + ((u >> 16) & 1u)) >> 16;   // RNE
    return (unsigned short)u;
}
__device__ __forceinline__ float bf2f(unsigned short h) {
    unsigned int u = ((unsigned int)h) << 16;
    return __builtin_bit_cast(float, u);
}

// ---------------- prepack ----------------
// [0, 393216) bytes: W A-frags bf16. mtg 0..31: KV rows 256+mtg*16; mtg 32..47: Q rows (mtg-32)*16.
//   idx = ((mtg*8+ks)*64+lane)*8+j <-> W[row(mtg)+(lane&15)][ks*32+(lane>>4)*8+j]
// [393216, 425984): posT bf16 [k=64][m=256]: posT[k*256+m] = bf16(pos[m*64+k])
__global__ __launch_bounds__(256) void prepack_w(const float* __restrict__ w,
                                                 const float* __restrict__ pos,
                                                 unsigned short* __restrict__ wp,
                                                 unsigned short* __restrict__ pT) {
    int gid = blockIdx.x * 256 + threadIdx.x;    // < 40960
    if (gid < 24576) {
        int lane = gid & 63;
        int ks   = (gid >> 6) & 7;
        int mtg  = gid >> 9;                     // 0..47
        int row  = (mtg < 32 ? 256 + mtg * 16 : (mtg - 32) * 16) + (lane & 15);
        int k0   = ks * 32 + (lane >> 4) * 8;
        const float* src = w + row * 256 + k0;
        short8 v;
#pragma unroll
        for (int j = 0; j < 8; ++j) v[j] = (short)f2bf(src[j]);
        *reinterpret_cast<short8*>(wp + (size_t)gid * 8) = v;
    } else {
        int u = gid - 24576;                     // k*256 + m, < 16384
        pT[u] = f2bf(pos[(u & 255) * 64 + (u >> 8)]);
    }
}

// ---------------- main fused kernel: one WG per 8x8 tile, 4 waves ----------------
// Wave w owns: q rows [64w,64w+64), key rows [64w,64w+64), value rows [64w,64w+64),
// heads {2w, 2w+1}.  2 barriers total.  (R4 structure; staging burst + posT regs.)
template <bool PRE>
__global__ __launch_bounds__(256, 2) void attn_fused(
        const float* __restrict__ x, const float* __restrict__ proj_w,
        const float* __restrict__ proj_b, const float* __restrict__ pos,
        const unsigned short* __restrict__ wpack, const unsigned short* __restrict__ posT,
        float* __restrict__ out) {
    // s_main: union of x-tile (bf16 [p=64][c=256] swizzled, 32768B)
    //         and key-LDS  (bf16 [k=64][m=260] pad + XOR,   33280B)
    __shared__ __align__(16) unsigned char s_main[33280];
    __shared__ __align__(16) float s_qs[256];     // scale*(q + bias)
    __shared__ __align__(16) float s_attn[512];   // [head][k]
    __shared__ __align__(16) float s_vbias[256];

    const int t    = threadIdx.x;
    const int lane = t & 63;
    const int wave = t >> 6;
    const int l15  = lane & 15;
    const int l4   = lane >> 4;

    // XCD-chunked swizzle: XCD i gets tiles [i*256, i*256+256) = one full image
    int bid  = blockIdx.x;
    int tile = (bid & 7) * 256 + (bid >> 3);
    int b  = tile >> 8;
    int hq = (tile >> 4) & 15;
    int wq = tile & 15;
    int h0 = hq * 8, w0 = wq * 8;

    const float* xb = x + (size_t)b * 4194304 + (size_t)h0 * 128 + w0;

    s_vbias[t] = proj_b[512 + t];

    // ---- posT prefetch: this thread's 64 pos values (lane=k, cols wave*64..+64) ----
    // 128B contiguous per thread, L2-hot, 16 regs held for the kernel lifetime.
    short8 pos8[8];
    if (PRE) {
        const unsigned short* pr = posT + (size_t)lane * 256 + wave * 64;
#pragma unroll
        for (int i = 0; i < 8; ++i)
            pos8[i] = *reinterpret_cast<const short8*>(pr + i * 8);
    }

    // ---- stage x tile -> bf16 [p][c] swizzled LDS ----
    // Burst-issue ALL 32 float2 loads (regs die before GEMM), then pack+write.
    {
        const int p   = lane;
        const int pl  = lane & 1;
        const int px0 = lane & ~1;
        const float* xpx = xb + (px0 >> 3) * 128 + (px0 & 7);
        float2 v[32];
#pragma unroll
        for (int h = 0; h < 8; ++h)
#pragma unroll
            for (int j = 0; j < 4; ++j) {
                int c = h * 32 + wave * 8 + 2 * j + pl;
                v[h * 4 + j] = *reinterpret_cast<const float2*>(xpx + (size_t)c * 16384);
            }
#pragma unroll
        for (int h = 0; h < 8; ++h) {
            uint4 pk;
            unsigned int* pku = &pk.x;
#pragma unroll
            for (int j = 0; j < 4; ++j) {
                float2 w2 = v[h * 4 + j];
                float sel   = pl ? w2.x : w2.y;
                float other = __shfl_xor(sel, 1);
                pku[j] = pl ? pk2bf(other, w2.y) : pk2bf(w2.x, other);
            }
            int c8 = h * 4 + wave;
            *reinterpret_cast<uint4*>(s_main + p * 512 + ((c8 * 16) ^ ((p & 7) << 4))) = pk;
        }
    }
    __syncthreads();

    // ---- pass 1: keys (rows 256..511) + q (rows 0..255, B-cols 0..15) ----
    f32x4 acc[4][4];
    f32x4 accQ[4];
#pragma unroll
    for (int mt = 0; mt < 4; ++mt) {
        accQ[mt] = (f32x4){0.f, 0.f, 0.f, 0.f};
#pragma unroll
        for (int nt = 0; nt < 4; ++nt) acc[mt][nt] = (f32x4){0.f, 0.f, 0.f, 0.f};
    }

#pragma unroll 2
    for (int ks = 0; ks < 8; ++ks) {
        short8 bfr[4];
#pragma unroll
        for (int nt = 0; nt < 4; ++nt) {
            int n  = nt * 16 + l15;
            int kb = ks * 32 + l4 * 8;
            bfr[nt] = *reinterpret_cast<const short8*>(
                s_main + n * 512 + ((2 * kb) ^ ((n & 7) << 4)));
        }
        short8 afk[4], afq[4];
#pragma unroll
        for (int mt = 0; mt < 4; ++mt) {
            if (PRE) {
                afk[mt] = *reinterpret_cast<const short8*>(
                    wpack + ((size_t)(((wave * 4 + mt) * 8 + ks) * 64 + lane)) * 8);
                afq[mt] = *reinterpret_cast<const short8*>(
                    wpack + ((size_t)(((32 + wave * 4 + mt) * 8 + ks) * 64 + lane)) * 8);
            } else {
                const float* wk = proj_w + (256 + (wave * 4 + mt) * 16 + l15) * 256 + ks * 32 + l4 * 8;
                const float* wq2 = proj_w + ((wave * 4 + mt) * 16 + l15) * 256 + ks * 32 + l4 * 8;
#pragma unroll
                for (int j = 0; j < 8; ++j) { afk[mt][j] = (short)f2bf(wk[j]); afq[mt][j] = (short)f2bf(wq2[j]); }
            }
        }
#pragma unroll
        for (int mt = 0; mt < 4; ++mt)
#pragma unroll
            for (int nt = 0; nt < 4; ++nt)
                acc[mt][nt] = __builtin_amdgcn_mfma_f32_16x16x32_bf16(afk[mt], bfr[nt], acc[mt][nt], 0, 0, 0);
#pragma unroll
        for (int mt = 0; mt < 4; ++mt)
            accQ[mt] = __builtin_amdgcn_mfma_f32_16x16x32_bf16(afq[mt], bfr[0], accQ[mt], 0, 0, 0);
    }

    // q: C-frag col = l15; pixel 0 = col 0
    if (l15 == 0) {
#pragma unroll
        for (int mt = 0; mt < 4; ++mt)
#pragma unroll
            for (int i = 0; i < 4; ++i) {
                int row = wave * 64 + mt * 16 + l4 * 4 + i;
                s_qs[row] = SCALE * (accQ[mt][i] + proj_b[row]);
            }
    }

    // pack keys to bf16 (no key bias: softmax shift-invariant)
    unsigned int kpk[4][4][2];
#pragma unroll
    for (int mt = 0; mt < 4; ++mt)
#pragma unroll
        for (int nt = 0; nt < 4; ++nt) {
            kpk[mt][nt][0] = pk2bf(acc[mt][nt][0], acc[mt][nt][1]);
            kpk[mt][nt][1] = pk2bf(acc[mt][nt][2], acc[mt][nt][3]);
        }

    // ---- pass 2: values (rows 512..767), reuse acc ----
#pragma unroll
    for (int mt = 0; mt < 4; ++mt)
#pragma unroll
        for (int nt = 0; nt < 4; ++nt) acc[mt][nt] = (f32x4){0.f, 0.f, 0.f, 0.f};
#pragma unroll 2
    for (int ks = 0; ks < 8; ++ks) {
        short8 bfr[4];
#pragma unroll
        for (int nt = 0; nt < 4; ++nt) {
            int n  = nt * 16 + l15;
            int kb = ks * 32 + l4 * 8;
            bfr[nt] = *reinterpret_cast<const short8*>(
                s_main + n * 512 + ((2 * kb) ^ ((n & 7) << 4)));
        }
        short8 afv[4];
#pragma unroll
        for (int mt = 0; mt < 4; ++mt) {
            if (PRE) {
                afv[mt] = *reinterpret_cast<const short8*>(
                    wpack + ((size_t)(((16 + wave * 4 + mt) * 8 + ks) * 64 + lane)) * 8);
            } else {
                const float* wv = proj_w + (512 + (wave * 4 + mt) * 16 + l15) * 256 + ks * 32 + l4 * 8;
#pragma unroll
                for (int j = 0; j < 8; ++j) afv[mt][j] = (short)f2bf(wv[j]);
            }
        }
#pragma unroll
        for (int mt = 0; mt < 4; ++mt)
#pragma unroll
            for (int nt = 0; nt < 4; ++nt)
                acc[mt][nt] = __builtin_amdgcn_mfma_f32_16x16x32_bf16(afv[mt], bfr[nt], acc[mt][nt], 0, 0, 0);
    }

    __syncthreads();   // all waves done reading x tile; s_main becomes key-LDS

    // ---- write own key rows to LDS [k=64][m=260], 8B-granular XOR on column ----
#pragma unroll
    for (int mt = 0; mt < 4; ++mt) {
        int m0 = wave * 64 + mt * 16 + l4 * 4;
#pragma unroll
        for (int nt = 0; nt < 4; ++nt) {
            int k = nt * 16 + l15;
            uint2 w2; w2.x = kpk[mt][nt][0]; w2.y = kpk[mt][nt][1];
            *reinterpret_cast<uint2*>(s_main + k * 520 + ((2 * m0) ^ (nt << 3))) = w2;
        }
    }
    // wave reads only its own rows below -> no barrier (compiler lgkmcnt ordering)

    // ---- softmax: heads 2w, 2w+1; lane = key index; pos from regs, keys b64 ----
    {
        const int k  = lane;
        const int xv = ((k >> 4) & 3) << 3;
        const unsigned char* krow = s_main + k * 520;
        float lg0 = 0.f, lg1 = 0.f;
#pragma unroll
        for (int d4 = 0; d4 < 8; ++d4) {
            short4v kv0 = *reinterpret_cast<const short4v*>(krow + ((2 * (wave * 64 + d4 * 4)) ^ xv));
            short4v kv1 = *reinterpret_cast<const short4v*>(krow + ((2 * (wave * 64 + 32 + d4 * 4)) ^ xv));
#pragma unroll
            for (int u = 0; u < 4; ++u) {
                const int d = d4 * 4 + u;
                const int o0 = wave * 64 + d;
                float q0 = s_qs[o0], q1 = s_qs[o0 + 32];
                float p0 = PRE ? bf2f((unsigned short)pos8[d >> 3][d & 7])
                               : pos[(size_t)o0 * 64 + k];
                float p1 = PRE ? bf2f((unsigned short)pos8[(d + 32) >> 3][d & 7])
                               : pos[(size_t)(o0 + 32) * 64 + k];
                lg0 = fmaf(q0, fmaf(SCALE, bf2f((unsigned short)kv0[u]), p0), lg0);
                lg1 = fmaf(q1, fmaf(SCALE, bf2f((unsigned short)kv1[u]), p1), lg1);
            }
        }
        float m0v = lg0, m1v = lg1;
#pragma unroll
        for (int off = 32; off >= 1; off >>= 1) {
            m0v = fmaxf(m0v, __shfl_xor(m0v, off));
            m1v = fmaxf(m1v, __shfl_xor(m1v, off));
        }
        float e0 = __expf(lg0 - m0v), e1 = __expf(lg1 - m1v);
        float s0 = e0, s1 = e1;
#pragma unroll
        for (int off = 32; off >= 1; off >>= 1) {
            s0 += __shfl_xor(s0, off);
            s1 += __shfl_xor(s1, off);
        }
        s_attn[(2 * wave) * 64 + k]     = e0 / s0;
        s_attn[(2 * wave + 1) * 64 + k] = e1 / s1;
    }
    // same-wave RAW on s_attn -> no barrier

    // ---- epilogue: out = attn @ values from own acc; Σattn=1 folds value bias ----
#pragma unroll
    for (int mt = 0; mt < 4; ++mt) {
        int head = 2 * wave + (mt >> 1);
        const float* ap = s_attn + head * 64;
        float a0 = ap[l15], a1 = ap[16 + l15], a2 = ap[32 + l15], a3 = ap[48 + l15];
#pragma unroll
        for (int i = 0; i < 4; ++i) {
            float sum = a0 * acc[mt][0][i] + a1 * acc[mt][1][i]
                      + a2 * acc[mt][2][i] + a3 * acc[mt][3][i];
            sum += __shfl_xor(sum, 1);
            sum += __shfl_xor(sum, 2);
            sum += __shfl_xor(sum, 4);
            sum += __shfl_xor(sum, 8);
            if (l15 == 0) {
                int vr = wave * 64 + mt * 16 + l4 * 4 + i;
                out[(size_t)b * 65536 + (size_t)vr * 256 + hq * 16 + wq] = sum + s_vbias[vr];
            }
        }
    }
}

extern "C" void kernel_launch(void* const* d_in, const int* in_sizes, int n_in,
                              void* d_out, int out_size, void* d_ws, size_t ws_size,
                              hipStream_t stream) {
    (void)in_sizes; (void)n_in; (void)out_size;
    const float* x      = (const float*)d_in[0];
    const float* proj_w = (const float*)d_in[1];
    const float* proj_b = (const float*)d_in[2];
    const float* pos    = (const float*)d_in[3];
    float* out = (float*)d_out;

    const size_t need_ws = 393216 + 32768;   // A-frags bf16 + posT bf16
    if (d_ws != nullptr && ws_size >= need_ws) {
        unsigned short* wp = (unsigned short*)d_ws;
        unsigned short* pT = (unsigned short*)((char*)d_ws + 393216);
        prepack_w<<<160, 256, 0, stream>>>(proj_w, pos, wp, pT);
        attn_fused<true><<<2048, 256, 0, stream>>>(x, proj_w, proj_b, pos, wp, pT, out);
    } else {
        attn_fused<false><<<2048, 256, 0, stream>>>(x, proj_w, proj_b, pos, nullptr, nullptr, out);
    }
}

// Round 8
// 92.578 us; speedup vs baseline: 4.9989x; 1.4051x over previous
//
#include <hip/hip_runtime.h>
#include <hip/hip_bf16.h>
#include <cstdint>
#include <cstddef>

#define SCALE 0.42044820762685725f  // 32^(-1/4)

typedef __attribute__((ext_vector_type(8))) short short8;
typedef __attribute__((ext_vector_type(4))) short short4v;
typedef __attribute__((ext_vector_type(4))) float f32x4;

__device__ __forceinline__ unsigned int pk2bf(float lo, float hi) {
    __hip_bfloat162 h = __float22bfloat162_rn(float2{lo, hi});  // v_cvt_pk_bf16_f32
    unsigned int u;
    __builtin_memcpy(&u, &h, sizeof(u));
    return u;
}
__device__ __forceinline__ unsigned short f2bf(float f) {
    unsigned int u = __builtin_bit_cast(unsigned int, f);
    u = (u + 0x7fffu + ((u >> 16) & 1u)) >> 16;   // RNE
    return (unsigned short)u;
}
__device__ __forceinline__ float bf2f(unsigned short h) {
    unsigned int u = ((unsigned int)h) << 16;
    return __builtin_bit_cast(float, u);
}

// ---------------- prepack ----------------
// [0, 393216) bytes: W A-frags bf16. mtg 0..31: KV rows 256+mtg*16; mtg 32..47: Q rows (mtg-32)*16.
//   idx = ((mtg*8+ks)*64+lane)*8+j <-> W[row(mtg)+(lane&15)][ks*32+(lane>>4)*8+j]
// [393216, 425984): posT bf16 [k=64][m=256]: posT[k*256+m] = bf16(pos[m*64+k])
__global__ __launch_bounds__(256) void prepack_w(const float* __restrict__ w,
                                                 const float* __restrict__ pos,
                                                 unsigned short* __restrict__ wp,
                                                 unsigned short* __restrict__ pT) {
    int gid = blockIdx.x * 256 + threadIdx.x;    // < 40960
    if (gid < 24576) {
        int lane = gid & 63;
        int ks   = (gid >> 6) & 7;
        int mtg  = gid >> 9;                     // 0..47
        int row  = (mtg < 32 ? 256 + mtg * 16 : (mtg - 32) * 16) + (lane & 15);
        int k0   = ks * 32 + (lane >> 4) * 8;
        const float* src = w + row * 256 + k0;
        short8 v;
#pragma unroll
        for (int j = 0; j < 8; ++j) v[j] = (short)f2bf(src[j]);
        *reinterpret_cast<short8*>(wp + (size_t)gid * 8) = v;
    } else {
        int u = gid - 24576;                     // k*256 + m, < 16384
        pT[u] = f2bf(pos[(u & 255) * 64 + (u >> 8)]);
    }
}

// ---------------- main fused kernel: one 512-thread WG per 8x8 tile, 8 waves ----------------
// Wave w owns HEAD w entirely: q rows [32w,32w+32), key rows [32w,32w+32) (of K-block),
// value rows [32w,32w+32).  2 barriers total; attention epilogue via shfl broadcast.
template <bool PRE>
__global__ __launch_bounds__(512, 4) void attn_fused(
        const float* __restrict__ x, const float* __restrict__ proj_w,
        const float* __restrict__ proj_b, const float* __restrict__ pos,
        const unsigned short* __restrict__ wpack, const unsigned short* __restrict__ posT,
        float* __restrict__ out) {
    // s_main: union of x-tile (bf16 [p=64][c=256] swizzled, 32768B)
    //         and key-LDS  (bf16 [k=64][m=260] pad + XOR,   33280B)
    __shared__ __align__(16) unsigned char s_main[33280];
    __shared__ __align__(16) float s_qs[256];     // scale*(q + bias)
    __shared__ __align__(16) float s_vbias[256];

    const int t    = threadIdx.x;
    const int lane = t & 63;
    const int wave = t >> 6;          // 0..7 = head id
    const int l15  = lane & 15;
    const int l4   = lane >> 4;

    // XCD-chunked swizzle: XCD i gets tiles [i*256, i*256+256) = one full image
    int bid  = blockIdx.x;
    int tile = (bid & 7) * 256 + (bid >> 3);
    int b  = tile >> 8;
    int hq = (tile >> 4) & 15;
    int wq = tile & 15;
    int h0 = hq * 8, w0 = wq * 8;

    const float* xb = x + (size_t)b * 4194304 + (size_t)h0 * 128 + w0;

    if (t < 256) s_vbias[t] = proj_b[512 + t];

    // ---- posT prefetch: lane=k, this head's 32 dims. 64B contiguous, L2-hot, 8 regs ----
    short8 pos8[4];
    if (PRE) {
        const unsigned short* pr = posT + (size_t)lane * 256 + wave * 32;
#pragma unroll
        for (int i = 0; i < 4; ++i)
            pos8[i] = *reinterpret_cast<const short8*>(pr + i * 8);
    }

    // ---- stage x tile -> bf16 [p][c] swizzled LDS (16 float2 loads/thread, burst) ----
    {
        const int p   = lane;
        const int pl  = lane & 1;
        const int px0 = lane & ~1;
        const float* xpx = xb + (px0 >> 3) * 128 + (px0 & 7);
        float2 v[16];
#pragma unroll
        for (int g = 0; g < 4; ++g)
#pragma unroll
            for (int j = 0; j < 4; ++j) {
                int c = (g * 8 + wave) * 8 + 2 * j + pl;
                v[g * 4 + j] = *reinterpret_cast<const float2*>(xpx + (size_t)c * 16384);
            }
#pragma unroll
        for (int g = 0; g < 4; ++g) {
            uint4 pk;
            unsigned int* pku = &pk.x;
#pragma unroll
            for (int j = 0; j < 4; ++j) {
                float2 w2 = v[g * 4 + j];
                float sel   = pl ? w2.x : w2.y;
                float other = __shfl_xor(sel, 1);
                pku[j] = pl ? pk2bf(other, w2.y) : pk2bf(w2.x, other);
            }
            int c8 = g * 8 + wave;
            *reinterpret_cast<uint4*>(s_main + p * 512 + ((c8 * 16) ^ ((p & 7) << 4))) = pk;
        }
    }
    __syncthreads();

    // ---- pass 1: keys (rows 256+32w..+32) + q (rows 32w..+32, B-cols 0..15) ----
    f32x4 acc[2][4];
    f32x4 accQ[2];
#pragma unroll
    for (int mt = 0; mt < 2; ++mt) {
        accQ[mt] = (f32x4){0.f, 0.f, 0.f, 0.f};
#pragma unroll
        for (int nt = 0; nt < 4; ++nt) acc[mt][nt] = (f32x4){0.f, 0.f, 0.f, 0.f};
    }

#pragma unroll 2
    for (int ks = 0; ks < 8; ++ks) {
        short8 bfr[4];
#pragma unroll
        for (int nt = 0; nt < 4; ++nt) {
            int n  = nt * 16 + l15;
            int kb = ks * 32 + l4 * 8;
            bfr[nt] = *reinterpret_cast<const short8*>(
                s_main + n * 512 + ((2 * kb) ^ ((n & 7) << 4)));
        }
        short8 afk[2], afq[2];
#pragma unroll
        for (int mt = 0; mt < 2; ++mt) {
            if (PRE) {
                afk[mt] = *reinterpret_cast<const short8*>(
                    wpack + ((size_t)(((wave * 2 + mt) * 8 + ks) * 64 + lane)) * 8);
                afq[mt] = *reinterpret_cast<const short8*>(
                    wpack + ((size_t)(((32 + wave * 2 + mt) * 8 + ks) * 64 + lane)) * 8);
            } else {
                const float* wk = proj_w + (256 + (wave * 2 + mt) * 16 + l15) * 256 + ks * 32 + l4 * 8;
                const float* wq2 = proj_w + ((wave * 2 + mt) * 16 + l15) * 256 + ks * 32 + l4 * 8;
#pragma unroll
                for (int j = 0; j < 8; ++j) { afk[mt][j] = (short)f2bf(wk[j]); afq[mt][j] = (short)f2bf(wq2[j]); }
            }
        }
#pragma unroll
        for (int mt = 0; mt < 2; ++mt)
#pragma unroll
            for (int nt = 0; nt < 4; ++nt)
                acc[mt][nt] = __builtin_amdgcn_mfma_f32_16x16x32_bf16(afk[mt], bfr[nt], acc[mt][nt], 0, 0, 0);
#pragma unroll
        for (int mt = 0; mt < 2; ++mt)
            accQ[mt] = __builtin_amdgcn_mfma_f32_16x16x32_bf16(afq[mt], bfr[0], accQ[mt], 0, 0, 0);
    }

    // q: C-frag col = l15; pixel 0 = col 0
    if (l15 == 0) {
#pragma unroll
        for (int mt = 0; mt < 2; ++mt)
#pragma unroll
            for (int i = 0; i < 4; ++i) {
                int row = wave * 32 + mt * 16 + l4 * 4 + i;
                s_qs[row] = SCALE * (accQ[mt][i] + proj_b[row]);
            }
    }

    // pack keys to bf16 (no key bias: softmax shift-invariant)
    unsigned int kpk[2][4][2];
#pragma unroll
    for (int mt = 0; mt < 2; ++mt)
#pragma unroll
        for (int nt = 0; nt < 4; ++nt) {
            kpk[mt][nt][0] = pk2bf(acc[mt][nt][0], acc[mt][nt][1]);
            kpk[mt][nt][1] = pk2bf(acc[mt][nt][2], acc[mt][nt][3]);
        }

    // ---- pass 2: values (rows 512+32w..+32), reuse acc ----
#pragma unroll
    for (int mt = 0; mt < 2; ++mt)
#pragma unroll
        for (int nt = 0; nt < 4; ++nt) acc[mt][nt] = (f32x4){0.f, 0.f, 0.f, 0.f};
#pragma unroll 2
    for (int ks = 0; ks < 8; ++ks) {
        short8 bfr[4];
#pragma unroll
        for (int nt = 0; nt < 4; ++nt) {
            int n  = nt * 16 + l15;
            int kb = ks * 32 + l4 * 8;
            bfr[nt] = *reinterpret_cast<const short8*>(
                s_main + n * 512 + ((2 * kb) ^ ((n & 7) << 4)));
        }
        short8 afv[2];
#pragma unroll
        for (int mt = 0; mt < 2; ++mt) {
            if (PRE) {
                afv[mt] = *reinterpret_cast<const short8*>(
                    wpack + ((size_t)(((16 + wave * 2 + mt) * 8 + ks) * 64 + lane)) * 8);
            } else {
                const float* wv = proj_w + (512 + (wave * 2 + mt) * 16 + l15) * 256 + ks * 32 + l4 * 8;
#pragma unroll
                for (int j = 0; j < 8; ++j) afv[mt][j] = (short)f2bf(wv[j]);
            }
        }
#pragma unroll
        for (int mt = 0; mt < 2; ++mt)
#pragma unroll
            for (int nt = 0; nt < 4; ++nt)
                acc[mt][nt] = __builtin_amdgcn_mfma_f32_16x16x32_bf16(afv[mt], bfr[nt], acc[mt][nt], 0, 0, 0);
    }

    __syncthreads();   // all waves done reading x tile; s_main becomes key-LDS

    // ---- write own key columns to LDS [k=64][m=260], 8B-granular XOR ----
#pragma unroll
    for (int mt = 0; mt < 2; ++mt) {
        int m0 = wave * 32 + mt * 16 + l4 * 4;
#pragma unroll
        for (int nt = 0; nt < 4; ++nt) {
            int k = nt * 16 + l15;
            uint2 w2; w2.x = kpk[mt][nt][0]; w2.y = kpk[mt][nt][1];
            *reinterpret_cast<uint2*>(s_main + k * 520 + ((2 * m0) ^ (nt << 3))) = w2;
        }
    }
    // wave reads only its own columns below -> no barrier (same-wave LDS ordering)

    // ---- softmax: one head per wave; lane = key index ----
    float attnw;
    {
        const int k  = lane;
        const int xv = ((k >> 4) & 3) << 3;
        const unsigned char* krow = s_main + (size_t)k * 520;
        float lg = 0.f;
#pragma unroll
        for (int d4 = 0; d4 < 8; ++d4) {
            short4v kv = *reinterpret_cast<const short4v*>(
                krow + ((2 * (wave * 32 + d4 * 4)) ^ xv));
#pragma unroll
            for (int u = 0; u < 4; ++u) {
                const int d = d4 * 4 + u;
                float q = s_qs[wave * 32 + d];
                float pf = PRE ? bf2f((unsigned short)pos8[d >> 3][d & 7])
                               : pos[(size_t)(wave * 32 + d) * 64 + k];
                lg = fmaf(q, fmaf(SCALE, bf2f((unsigned short)kv[u]), pf), lg);
            }
        }
        float mx = lg;
#pragma unroll
        for (int off = 32; off >= 1; off >>= 1) mx = fmaxf(mx, __shfl_xor(mx, off));
        float e = __expf(lg - mx);
        float s = e;
#pragma unroll
        for (int off = 32; off >= 1; off >>= 1) s += __shfl_xor(s, off);
        attnw = e / s;
    }

    // ---- epilogue: out = attn @ values from own acc; Σattn=1 folds value bias ----
    {
        float a0 = __shfl(attnw, l15);
        float a1 = __shfl(attnw, 16 + l15);
        float a2 = __shfl(attnw, 32 + l15);
        float a3 = __shfl(attnw, 48 + l15);
#pragma unroll
        for (int mt = 0; mt < 2; ++mt) {
#pragma unroll
            for (int i = 0; i < 4; ++i) {
                float sum = a0 * acc[mt][0][i] + a1 * acc[mt][1][i]
                          + a2 * acc[mt][2][i] + a3 * acc[mt][3][i];
                sum += __shfl_xor(sum, 1);
                sum += __shfl_xor(sum, 2);
                sum += __shfl_xor(sum, 4);
                sum += __shfl_xor(sum, 8);
                if (l15 == 0) {
                    int vr = wave * 32 + mt * 16 + l4 * 4 + i;
                    out[(size_t)b * 65536 + (size_t)vr * 256 + hq * 16 + wq] = sum + s_vbias[vr];
                }
            }
        }
    }
}

extern "C" void kernel_launch(void* const* d_in, const int* in_sizes, int n_in,
                              void* d_out, int out_size, void* d_ws, size_t ws_size,
                              hipStream_t stream) {
    (void)in_sizes; (void)n_in; (void)out_size;
    const float* x      = (const float*)d_in[0];
    const float* proj_w = (const float*)d_in[1];
    const float* proj_b = (const float*)d_in[2];
    const float* pos    = (const float*)d_in[3];
    float* out = (float*)d_out;

    const size_t need_ws = 393216 + 32768;   // A-frags bf16 + posT bf16
    if (d_ws != nullptr && ws_size >= need_ws) {
        unsigned short* wp = (unsigned short*)d_ws;
        unsigned short* pT = (unsigned short*)((char*)d_ws + 393216);
        prepack_w<<<160, 256, 0, stream>>>(proj_w, pos, wp, pT);
        attn_fused<true><<<2048, 512, 0, stream>>>(x, proj_w, proj_b, pos, wp, pT, out);
    } else {
        attn_fused<false><<<2048, 512, 0, stream>>>(x, proj_w, proj_b, pos, nullptr, nullptr, out);
    }
}

// Round 9
// 85.439 us; speedup vs baseline: 5.4166x; 1.0836x over previous
//
#include <hip/hip_runtime.h>
#include <hip/hip_bf16.h>
#include <cstdint>
#include <cstddef>

#define SCALE 0.42044820762685725f  // 32^(-1/4)

typedef __attribute__((ext_vector_type(8))) short short8;
typedef __attribute__((ext_vector_type(4))) short short4v;
typedef __attribute__((ext_vector_type(4))) float f32x4;

__device__ __forceinline__ unsigned int pk2bf(float lo, float hi) {
    __hip_bfloat162 h = __float22bfloat162_rn(float2{lo, hi});  // v_cvt_pk_bf16_f32
    unsigned int u;
    __builtin_memcpy(&u, &h, sizeof(u));
    return u;
}
__device__ __forceinline__ unsigned short f2bf(float f) {
    unsigned int u = __builtin_bit_cast(unsigned int, f);
    u = (u + 0x7fffu + ((u >> 16) & 1u)) >> 16;   // RNE
    return (unsigned short)u;
}
__device__ __forceinline__ float bf2f(unsigned short h) {
    unsigned int u = ((unsigned int)h) << 16;
    return __builtin_bit_cast(float, u);
}

// ---------------- ws layout ----------------
// [0,      393216) : W A-frags bf16 (mtg 0..15 K rows 256+16m; 16..31 V rows 512+16m; 32..47 Q rows m*16 — Q frags used only by !PRE fallback)
// [393216, 425984) : posT bf16 [k=64][m=256]
// [425984, 688128) : WqT fp32 [c=256][o=256]
// [688128, 2785280): q_all fp32 [tile=2048][o=256] = scale*(Wq@X0 + bq)

__global__ __launch_bounds__(256) void prepack_w(const float* __restrict__ w,
                                                 const float* __restrict__ pos,
                                                 unsigned short* __restrict__ wp,
                                                 unsigned short* __restrict__ pT,
                                                 float* __restrict__ wqT) {
    int gid = blockIdx.x * 256 + threadIdx.x;    // < 106496
    if (gid < 24576) {
        int lane = gid & 63;
        int ks   = (gid >> 6) & 7;
        int mtg  = gid >> 9;                     // 0..47
        int row  = (mtg < 32 ? 256 + mtg * 16 : (mtg - 32) * 16) + (lane & 15);
        int k0   = ks * 32 + (lane >> 4) * 8;
        const float* src = w + row * 256 + k0;
        short8 v;
#pragma unroll
        for (int j = 0; j < 8; ++j) v[j] = (short)f2bf(src[j]);
        *reinterpret_cast<short8*>(wp + (size_t)gid * 8) = v;
    } else if (gid < 40960) {
        int u = gid - 24576;                     // k*256 + m
        pT[u] = f2bf(pos[(u & 255) * 64 + (u >> 8)]);
    } else {
        int u = gid - 40960;                     // c*256 + o, < 65536
        wqT[u] = w[(u & 255) * 256 + (u >> 8)];
    }
}

// ---------------- q kernel: q_all[tile][o] = scale*(Wq[o]·x[:,p0(tile)] + bq[o]) ----------------
__global__ __launch_bounds__(256) void q_kernel(const float* __restrict__ x,
                                                const float* __restrict__ wqT,
                                                const float* __restrict__ proj_b,
                                                float* __restrict__ q_all) {
    __shared__ float s_x0[4][256];
    const int t = threadIdx.x;
    const int tile0 = blockIdx.x * 4;            // 4 tiles share (b,hq)
    const int b = tile0 >> 8, hq = (tile0 >> 4) & 15, wq0 = tile0 & 15;
    {
        const float* src = x + (size_t)b * 4194304 + (size_t)t * 16384 + hq * 1024 + wq0 * 8;
#pragma unroll
        for (int j = 0; j < 4; ++j) s_x0[j][t] = src[j * 8];
    }
    __syncthreads();
    float acc[4] = {0.f, 0.f, 0.f, 0.f};
#pragma unroll 8
    for (int c = 0; c < 256; ++c) {
        float wv = wqT[c * 256 + t];             // coalesced; LDS reads broadcast
#pragma unroll
        for (int j = 0; j < 4; ++j) acc[j] = fmaf(wv, s_x0[j][c], acc[j]);
    }
    float bq = proj_b[t];
#pragma unroll
    for (int j = 0; j < 4; ++j)
        q_all[(size_t)(tile0 + j) * 256 + t] = SCALE * (acc[j] + bq);
}

// ---------------- main fused kernel: one 512-thread WG per tile, 8 waves ----------------
// Wave w = head w. Single K+V MFMA pass: acc[0..1]=K rows, acc[2..3]=V rows (both fp32).
// Attention fully in-register (keys never leave acc). ONE barrier.
template <bool PRE>
__global__ __launch_bounds__(512, 4) void attn_fused(
        const float* __restrict__ x, const float* __restrict__ proj_w,
        const float* __restrict__ proj_b, const float* __restrict__ pos,
        const unsigned short* __restrict__ wpack, const unsigned short* __restrict__ posT,
        const float* __restrict__ q_all, float* __restrict__ out) {
    __shared__ __align__(16) unsigned char s_main[32768];  // x-tile bf16 [p=64][c=256] swizzled
    __shared__ __align__(16) float s_vbias[256];
    __shared__ __align__(16) float s_qs[256];              // !PRE only

    const int t    = threadIdx.x;
    const int lane = t & 63;
    const int wave = t >> 6;          // head id
    const int l15  = lane & 15;
    const int l4   = lane >> 4;

    // XCD-chunked swizzle
    int bid  = blockIdx.x;
    int tile = (bid & 7) * 256 + (bid >> 3);
    int b  = tile >> 8;
    int hq = (tile >> 4) & 15;
    int wq = tile & 15;

    const float* xb = x + (size_t)b * 4194304 + (size_t)(hq * 8) * 128 + wq * 8;

    if (t < 256) s_vbias[t] = proj_b[512 + t];

    // ---- stage x tile -> bf16 [p][c] swizzled LDS (burst loads) ----
    {
        const int p   = lane;
        const int pl  = lane & 1;
        const int px0 = lane & ~1;
        const float* xpx = xb + (px0 >> 3) * 128 + (px0 & 7);
        float2 v[16];
#pragma unroll
        for (int g = 0; g < 4; ++g)
#pragma unroll
            for (int j = 0; j < 4; ++j) {
                int c = (g * 8 + wave) * 8 + 2 * j + pl;
                v[g * 4 + j] = *reinterpret_cast<const float2*>(xpx + (size_t)c * 16384);
            }
#pragma unroll
        for (int g = 0; g < 4; ++g) {
            uint4 pk;
            unsigned int* pku = &pk.x;
#pragma unroll
            for (int j = 0; j < 4; ++j) {
                float2 w2 = v[g * 4 + j];
                float sel   = pl ? w2.x : w2.y;
                float other = __shfl_xor(sel, 1);
                pku[j] = pl ? pk2bf(other, w2.y) : pk2bf(w2.x, other);
            }
            int c8 = g * 8 + wave;
            *reinterpret_cast<uint4*>(s_main + p * 512 + ((c8 * 16) ^ ((p & 7) << 4))) = pk;
        }
    }
    __syncthreads();   // the only barrier

    // ---- single pass: K (rows 256+32w..) -> acc[0..1], V (rows 512+32w..) -> acc[2..3] ----
    f32x4 acc[4][4];
#pragma unroll
    for (int mt = 0; mt < 4; ++mt)
#pragma unroll
        for (int nt = 0; nt < 4; ++nt) acc[mt][nt] = (f32x4){0.f, 0.f, 0.f, 0.f};
    f32x4 accQ[2];
    if (!PRE) {
#pragma unroll
        for (int mt = 0; mt < 2; ++mt) accQ[mt] = (f32x4){0.f, 0.f, 0.f, 0.f};
    }

#pragma unroll 2
    for (int ks = 0; ks < 8; ++ks) {
        short8 bfr[4];
#pragma unroll
        for (int nt = 0; nt < 4; ++nt) {
            int n  = nt * 16 + l15;
            int kb = ks * 32 + l4 * 8;
            bfr[nt] = *reinterpret_cast<const short8*>(
                s_main + n * 512 + ((2 * kb) ^ ((n & 7) << 4)));
        }
        short8 afk[2], afv[2];
#pragma unroll
        for (int mt = 0; mt < 2; ++mt) {
            if (PRE) {
                afk[mt] = *reinterpret_cast<const short8*>(
                    wpack + ((size_t)(((wave * 2 + mt) * 8 + ks) * 64 + lane)) * 8);
                afv[mt] = *reinterpret_cast<const short8*>(
                    wpack + ((size_t)(((16 + wave * 2 + mt) * 8 + ks) * 64 + lane)) * 8);
            } else {
                const float* wk = proj_w + (256 + (wave * 2 + mt) * 16 + l15) * 256 + ks * 32 + l4 * 8;
                const float* wv = proj_w + (512 + (wave * 2 + mt) * 16 + l15) * 256 + ks * 32 + l4 * 8;
#pragma unroll
                for (int j = 0; j < 8; ++j) { afk[mt][j] = (short)f2bf(wk[j]); afv[mt][j] = (short)f2bf(wv[j]); }
            }
        }
#pragma unroll
        for (int mt = 0; mt < 2; ++mt)
#pragma unroll
            for (int nt = 0; nt < 4; ++nt) {
                acc[mt][nt]     = __builtin_amdgcn_mfma_f32_16x16x32_bf16(afk[mt], bfr[nt], acc[mt][nt], 0, 0, 0);
                acc[2 + mt][nt] = __builtin_amdgcn_mfma_f32_16x16x32_bf16(afv[mt], bfr[nt], acc[2 + mt][nt], 0, 0, 0);
            }
        if (!PRE) {
            short8 afq[2];
#pragma unroll
            for (int mt = 0; mt < 2; ++mt) {
                const float* wq2 = proj_w + ((wave * 2 + mt) * 16 + l15) * 256 + ks * 32 + l4 * 8;
#pragma unroll
                for (int j = 0; j < 8; ++j) afq[mt][j] = (short)f2bf(wq2[j]);
                accQ[mt] = __builtin_amdgcn_mfma_f32_16x16x32_bf16(afq[mt], bfr[0], accQ[mt], 0, 0, 0);
            }
        }
    }

    if (!PRE) {
        // q: C-frag col = l15; pixel 0 = col 0 (same-wave LDS RAW, no barrier)
        if (l15 == 0) {
#pragma unroll
            for (int mt = 0; mt < 2; ++mt)
#pragma unroll
                for (int i = 0; i < 4; ++i) {
                    int row = wave * 32 + mt * 16 + l4 * 4 + i;
                    s_qs[row] = SCALE * (accQ[mt][i] + proj_b[row]);
                }
        }
    }

    // ---- softmax: one head per wave, fully in-register; keys = acc[0..1] fp32 ----
    // lane (l15,l4) holds K[d = mt*16+l4*4+i][key = nt*16+l15]
    float attnw[4];
    {
        float qf[2][4];
        if (PRE) {
            const float* qp = q_all + (size_t)tile * 256 + wave * 32 + l4 * 4;
#pragma unroll
            for (int mt = 0; mt < 2; ++mt) {
                float4 qv = *reinterpret_cast<const float4*>(qp + mt * 16);
                qf[mt][0] = qv.x; qf[mt][1] = qv.y; qf[mt][2] = qv.z; qf[mt][3] = qv.w;
            }
        } else {
#pragma unroll
            for (int mt = 0; mt < 2; ++mt)
#pragma unroll
                for (int i = 0; i < 4; ++i) qf[mt][i] = s_qs[wave * 32 + mt * 16 + l4 * 4 + i];
        }
        short4v pos4[4][2];
        if (PRE) {
#pragma unroll
            for (int nt = 0; nt < 4; ++nt)
#pragma unroll
                for (int mt = 0; mt < 2; ++mt)
                    pos4[nt][mt] = *reinterpret_cast<const short4v*>(
                        posT + (size_t)(nt * 16 + l15) * 256 + wave * 32 + mt * 16 + l4 * 4);
        }

        float lg[4];
#pragma unroll
        for (int nt = 0; nt < 4; ++nt) {
            float p = 0.f;
#pragma unroll
            for (int mt = 0; mt < 2; ++mt)
#pragma unroll
                for (int i = 0; i < 4; ++i) {
                    float pf = PRE ? bf2f((unsigned short)pos4[nt][mt][i])
                                   : pos[(size_t)(wave * 32 + mt * 16 + l4 * 4 + i) * 64 + nt * 16 + l15];
                    p = fmaf(qf[mt][i], fmaf(SCALE, acc[mt][nt][i], pf), p);
                }
            p += __shfl_xor(p, 16);   // sum the 4 l4 d-groups
            p += __shfl_xor(p, 32);
            lg[nt] = p;
        }
        float mx = fmaxf(fmaxf(lg[0], lg[1]), fmaxf(lg[2], lg[3]));
        mx = fmaxf(mx, __shfl_xor(mx, 1));
        mx = fmaxf(mx, __shfl_xor(mx, 2));
        mx = fmaxf(mx, __shfl_xor(mx, 4));
        mx = fmaxf(mx, __shfl_xor(mx, 8));
        float e0 = __expf(lg[0] - mx), e1 = __expf(lg[1] - mx);
        float e2 = __expf(lg[2] - mx), e3 = __expf(lg[3] - mx);
        float s = (e0 + e1) + (e2 + e3);
        s += __shfl_xor(s, 1);
        s += __shfl_xor(s, 2);
        s += __shfl_xor(s, 4);
        s += __shfl_xor(s, 8);
        float rs = 1.f / s;
        attnw[0] = e0 * rs; attnw[1] = e1 * rs; attnw[2] = e2 * rs; attnw[3] = e3 * rs;
    }

    // ---- epilogue: out = attn @ V from acc[2..3]; Σattn=1 folds value bias ----
#pragma unroll
    for (int mt = 0; mt < 2; ++mt) {
#pragma unroll
        for (int i = 0; i < 4; ++i) {
            float sum = attnw[0] * acc[2 + mt][0][i] + attnw[1] * acc[2 + mt][1][i]
                      + attnw[2] * acc[2 + mt][2][i] + attnw[3] * acc[2 + mt][3][i];
            sum += __shfl_xor(sum, 1);
            sum += __shfl_xor(sum, 2);
            sum += __shfl_xor(sum, 4);
            sum += __shfl_xor(sum, 8);
            if (l15 == 0) {
                int vr = wave * 32 + mt * 16 + l4 * 4 + i;
                out[(size_t)b * 65536 + (size_t)vr * 256 + hq * 16 + wq] = sum + s_vbias[vr];
            }
        }
    }
}

extern "C" void kernel_launch(void* const* d_in, const int* in_sizes, int n_in,
                              void* d_out, int out_size, void* d_ws, size_t ws_size,
                              hipStream_t stream) {
    (void)in_sizes; (void)n_in; (void)out_size;
    const float* x      = (const float*)d_in[0];
    const float* proj_w = (const float*)d_in[1];
    const float* proj_b = (const float*)d_in[2];
    const float* pos    = (const float*)d_in[3];
    float* out = (float*)d_out;

    const size_t OFF_POST = 393216;
    const size_t OFF_WQT  = 425984;
    const size_t OFF_QALL = 688128;
    const size_t need_ws  = OFF_QALL + 2097152;   // ~2.72 MB

    if (d_ws != nullptr && ws_size >= need_ws) {
        unsigned short* wp  = (unsigned short*)d_ws;
        unsigned short* pT  = (unsigned short*)((char*)d_ws + OFF_POST);
        float*          wqT = (float*)((char*)d_ws + OFF_WQT);
        float*          qA  = (float*)((char*)d_ws + OFF_QALL);
        prepack_w<<<416, 256, 0, stream>>>(proj_w, pos, wp, pT, wqT);
        q_kernel<<<512, 256, 0, stream>>>(x, wqT, proj_b, qA);
        attn_fused<true><<<2048, 512, 0, stream>>>(x, proj_w, proj_b, pos, wp, pT, qA, out);
    } else {
        attn_fused<false><<<2048, 512, 0, stream>>>(x, proj_w, proj_b, pos, nullptr, nullptr, nullptr, out);
    }
}